// Round 8
// baseline (333.722 us; speedup 1.0000x reference)
//
#include <hip/hip_runtime.h>
#include <hip/hip_bf16.h>
#include <stdint.h>

typedef __attribute__((ext_vector_type(8))) __bf16 bf16x8;
typedef __attribute__((ext_vector_type(4))) __bf16 bf16x4;
typedef __attribute__((ext_vector_type(4))) float f32x4;

#define B_  2
#define H_  16
#define S_  2048
#define D_  128
#define BH_ (B_*H_)

__device__ __forceinline__ uint32_t f2bf1(float f){
  uint32_t u = __builtin_bit_cast(uint32_t, f);
  return (u + 0x7fffu + ((u >> 16) & 1u)) >> 16;
}
__device__ __forceinline__ uint32_t pk2(float a, float b){
  return f2bf1(a) | (f2bf1(b) << 16);
}
__device__ __forceinline__ float bf2f(unsigned short u){
  return __builtin_bit_cast(float, (uint32_t)u << 16);
}

// async global->LDS, 16B/lane, linear LDS dest
__device__ __forceinline__ void gld16(const void* g, void* l){
  __builtin_amdgcn_global_load_lds(
      (const __attribute__((address_space(1))) void*)g,
      (__attribute__((address_space(3))) void*)(uintptr_t)l, 16, 0, 0);
}

// Split-mode unit table, LPT order (longest chunks first). code = qb*8 + c.
// nc(qb) = ceil((2qb+2)/8); chunks split the kv-tile range evenly (big first).
__device__ const unsigned char TAB_S[40] = {
  56,57,80,88,89,90,112,113,120,121,122,123,24,          // len 8
  48,49,72,73,81,82,96,97,104,105,106,107,114,115,       // len 7
  40,41,64,65,66,74,98,99,16,                            // len 6
  32,33, 8, 0                                            // len 5,5,4,2
};
// partial-slot prefix offsets for qb=4..15 (nc = 2,2,2,2,3,3,3,3,4,4,4,4)
__device__ const unsigned char OFFT[12] = {0,2,4,6,8,11,14,17,20,24,28,32};

// ---------- fused pre-pass: K->bf16, V->Vt (bf16 transposed), zero ctrl ----------
__global__ void prep(const float* __restrict__ K, const float* __restrict__ V,
                     unsigned short* __restrict__ Kb, unsigned short* __restrict__ Vt,
                     int* __restrict__ ctrl){
  __shared__ __attribute__((aligned(16))) unsigned short t[64*68];
  const int kv0 = blockIdx.x * 64, d0 = blockIdx.y * 64, bh = blockIdx.z;
  const int tid = threadIdx.x;
  if (blockIdx.x == 0 && blockIdx.y == 0 && blockIdx.z == 0 && tid < 128) ctrl[tid] = 0;
  const float* Vp = V + (size_t)bh * S_ * D_;
  const float* Kp = K + (size_t)bh * S_ * D_;
  unsigned short* Ko = Kb + (size_t)bh * S_ * D_;
  for (int i = 0; i < 4; i++){
    int f = tid + i*256;
    int kv = f >> 4, c4 = f & 15;
    size_t idx = (size_t)(kv0+kv)*D_ + d0 + c4*4;
    float4 k = *(const float4*)(Kp + idx);
    *(uint2*)(Ko + idx) = make_uint2(pk2(k.x,k.y), pk2(k.z,k.w));
  }
  for (int i = 0; i < 4; i++){
    int f = tid + i*256;
    int kv = f >> 4, c4 = f & 15;
    float4 v = *(const float4*)(Vp + (size_t)(kv0+kv)*D_ + d0 + c4*4);
    *(uint2*)&t[kv*68 + c4*4] = make_uint2(pk2(v.x,v.y), pk2(v.z,v.w));
  }
  __syncthreads();
  unsigned short* Vo = Vt + (size_t)bh * D_ * S_;
  for (int i = 0; i < 4; i++){
    int g = tid + i*256;
    int d = g >> 4, c = g & 15, kv = c*4;
    ushort4 o;
    o.x = t[(kv+0)*68 + d];
    o.y = t[(kv+1)*68 + d];
    o.z = t[(kv+2)*68 + d];
    o.w = t[(kv+3)*68 + d];
    *(ushort4*)(Vo + (size_t)(d0+d)*S_ + kv0 + kv) = o;
  }
}

// ---------- persistent flash-attention: single-buffer K/V, 48KB LDS, 3 blk/CU ----------
__global__ __launch_bounds__(256, 3)
void attn_fwd(const float* __restrict__ Q, const unsigned short* __restrict__ Kb,
              const unsigned short* __restrict__ Vt, float* __restrict__ Out,
              unsigned short* __restrict__ Opart, float* __restrict__ MLpart,
              int* __restrict__ ctrl, int splitFlag){
  __shared__ __attribute__((aligned(16))) unsigned short Klds[64*128];   // 16KB
  __shared__ __attribute__((aligned(16))) unsigned short Vlds[128*64];   // 16KB
  __shared__ __attribute__((aligned(16))) unsigned short Plds[4][2][16*64]; // 16KB
  int* s_u = (int*)&Plds[0][0][0];   // overlaid broadcast word

  const int xcd = blockIdx.x & 7;
  int* cnt = ctrl + xcd*16;
  const int NU = splitFlag ? 160 : 64;

  const int tid  = threadIdx.x;
  const int wave = tid >> 6, lane = tid & 63;
  const int ql   = lane & 15, hi = lane >> 4;
  const float qs = 0.08838834764831845f * 1.44269504088896f; // scale*log2(e)

  uint32_t koff[4], voff[4];
  #pragma unroll
  for (int i = 0; i < 4; i++){
    int kr = wave*16 + i*4 + (lane >> 4);
    koff[i] = kr*256 + (((lane & 15) ^ ((i & 1)*4 + (lane >> 4))) << 4);
    int vr = wave*32 + i*8 + (lane >> 3);
    voff[i] = vr*(S_*2) + (((lane & 7) ^ (lane >> 3)) << 4);
  }

  for (;;){
    if (tid == 0) *s_u = atomicAdd(cnt, 1);   // relaxed, non-blocking
    __syncthreads();
    const int u = *s_u;
    __syncthreads();
    if (u >= NU) break;

    int qb, c;
    if (splitFlag){ int e = TAB_S[u >> 2]; qb = e >> 3; c = e & 7; }
    else { qb = 15 - (u >> 2); c = 0; }
    const int bh = xcd + 8*(u & 3);
    const int nc = splitFlag ? ((2*qb + 9) >> 3) : 1;
    int t0, tEnd;
    if (nc == 1){ t0 = 0; tEnd = 2*qb + 2; }
    else {
      int tot = 2*qb + 2, sz = tot/nc, rem = tot%nc;
      t0 = c*sz + (c < rem ? c : rem);
      tEnd = t0 + sz + (c < rem ? 1 : 0);
    }
    const int wq0 = qb*128 + wave*32;
    const int dtw = 2*qb + (wave >> 1);   // global diagonal tile for this wave

    const char* Kg = (const char*)(Kb + (size_t)bh * S_ * D_);
    const char* Vg = (const char*)(Vt + (size_t)bh * D_ * S_);

    // Q fragments, pre-scaled (B-operand of swapped QK^T)
    uint4 qf[2][4];
    #pragma unroll
    for (int sub = 0; sub < 2; sub++){
      const float* Qp = Q + ((size_t)bh * S_ + (wq0 + sub*16 + ql)) * D_;
      #pragma unroll
      for (int ks = 0; ks < 4; ks++){
        float4 a = *(const float4*)(Qp + ks*32 + hi*8);
        float4 b = *(const float4*)(Qp + ks*32 + hi*8 + 4);
        bf16x8 q8;
        q8[0] = (__bf16)(a.x*qs); q8[1] = (__bf16)(a.y*qs);
        q8[2] = (__bf16)(a.z*qs); q8[3] = (__bf16)(a.w*qs);
        q8[4] = (__bf16)(b.x*qs); q8[5] = (__bf16)(b.y*qs);
        q8[6] = (__bf16)(b.z*qs); q8[7] = (__bf16)(b.w*qs);
        qf[sub][ks] = __builtin_bit_cast(uint4, q8);
      }
    }

    f32x4 o[2][8];
    #pragma unroll
    for (int sub = 0; sub < 2; sub++)
      #pragma unroll
      for (int nb = 0; nb < 8; nb++) o[sub][nb] = (f32x4)(0.f);
    float m_run[2] = {-INFINITY, -INFINITY};
    float l_run[2] = {0.f, 0.f};

    // stage tile t into the (single) K/V buffer
    auto stage = [&](int t){
      const char* kp = Kg + t*16384;
      const char* vp = Vg + t*128;
      char* kd = (char*)Klds + wave*4096;
      char* vd = (char*)Vlds + wave*4096;
      #pragma unroll
      for (int i = 0; i < 4; i++){
        gld16(kp + koff[i], kd + i*1024);
        gld16(vp + voff[i], vd + i*1024);
      }
    };

    stage(t0);
    for (int t = t0; t < tEnd; ++t){
      __syncthreads();                 // drains gld16 -> K/V tile ready
      if (t <= dtw){
        const int k0 = t*64;
        const bool diag = (t == dtw);

        // ---- swapped QK^T (mb-outer, R4 form)
        f32x4 sa[2][4];
        __builtin_amdgcn_s_setprio(1);
        #pragma unroll
        for (int mb = 0; mb < 4; mb++){
          sa[0][mb] = (f32x4)(0.f);
          sa[1][mb] = (f32x4)(0.f);
          const int row = ql + mb*16;
          #pragma unroll
          for (int ks = 0; ks < 4; ks++){
            int byte = (row*256 + ks*64 + hi*16) ^ ((row & 7) << 4);
            bf16x8 kf = *(const bf16x8*)((const char*)Klds + byte);
            sa[0][mb] = __builtin_amdgcn_mfma_f32_16x16x32_bf16(
                          kf, __builtin_bit_cast(bf16x8, qf[0][ks]), sa[0][mb], 0, 0, 0);
            sa[1][mb] = __builtin_amdgcn_mfma_f32_16x16x32_bf16(
                          kf, __builtin_bit_cast(bf16x8, qf[1][ks]), sa[1][mb], 0, 0, 0);
          }
        }
        __builtin_amdgcn_s_setprio(0);

        // ---- online softmax (log2 domain, defer-max)
        #pragma unroll
        for (int sub = 0; sub < 2; sub++){
          float p[16];
          float pm = -INFINITY;
          const int q_abs = wq0 + sub*16 + ql;
          #pragma unroll
          for (int mb = 0; mb < 4; mb++){
            #pragma unroll
            for (int r = 0; r < 4; r++){
              float s = sa[sub][mb][r];
              if (diag){
                int kv = k0 + mb*16 + hi*4 + r;
                if (kv > q_abs) s = -1e30f;
              }
              p[mb*4 + r] = s;
              pm = fmaxf(pm, s);
            }
          }
          pm = fmaxf(pm, __shfl_xor(pm, 16));
          pm = fmaxf(pm, __shfl_xor(pm, 32));
          if (__any(pm > m_run[sub] + 11.5f)){
            float mn  = fmaxf(m_run[sub], pm);
            float fac = exp2f(m_run[sub] - mn);
            float f0 = __shfl(fac, hi*4 + 0), f1 = __shfl(fac, hi*4 + 1);
            float f2 = __shfl(fac, hi*4 + 2), f3 = __shfl(fac, hi*4 + 3);
            #pragma unroll
            for (int nb = 0; nb < 8; nb++){
              o[sub][nb][0] *= f0; o[sub][nb][1] *= f1;
              o[sub][nb][2] *= f2; o[sub][nb][3] *= f3;
            }
            l_run[sub] *= fac;
            m_run[sub] = mn;
          }
          float rs = 0.f;
          #pragma unroll
          for (int q2 = 0; q2 < 16; q2++){ p[q2] = exp2f(p[q2] - m_run[sub]); rs += p[q2]; }
          rs += __shfl_xor(rs, 16);
          rs += __shfl_xor(rs, 32);
          l_run[sub] += rs;

          #pragma unroll
          for (int mb = 0; mb < 4; mb++){
            bf16x4 pv;
            pv[0] = (__bf16)p[mb*4+0]; pv[1] = (__bf16)p[mb*4+1];
            pv[2] = (__bf16)p[mb*4+2]; pv[3] = (__bf16)p[mb*4+3];
            int byte = (ql*128 + mb*32 + hi*8) ^ ((ql & 7) << 4);
            *(bf16x4*)((char*)&Plds[wave][sub][0] + byte) = pv;
          }
        }

        // ---- PV
        __builtin_amdgcn_s_setprio(1);
        #pragma unroll
        for (int ks = 0; ks < 2; ks++){
          int pb = (ql*128 + ks*64 + hi*16) ^ ((ql & 7) << 4);
          bf16x8 pfA = *(const bf16x8*)((const char*)&Plds[wave][0][0] + pb);
          bf16x8 pfB = *(const bf16x8*)((const char*)&Plds[wave][1][0] + pb);
          #pragma unroll
          for (int nb = 0; nb < 8; nb++){
            int d = ql + nb*16;
            int vb = (d*128 + ks*64 + hi*16) ^ ((d & 7) << 4);
            bf16x8 vf = *(const bf16x8*)((const char*)Vlds + vb);
            o[0][nb] = __builtin_amdgcn_mfma_f32_16x16x32_bf16(pfA, vf, o[0][nb], 0, 0, 0);
            o[1][nb] = __builtin_amdgcn_mfma_f32_16x16x32_bf16(pfB, vf, o[1][nb], 0, 0, 0);
          }
        }
        __builtin_amdgcn_s_setprio(0);
      }

      __syncthreads();                 // all reads of K/V done
      if (t + 1 < tEnd) stage(t + 1);  // overwrite buffer for next tile
    }

    // ---- epilogue
    if (nc == 1){
      #pragma unroll
      for (int sub = 0; sub < 2; sub++){
        float r0 = 1.f / __shfl(l_run[sub], hi*4 + 0);
        float r1 = 1.f / __shfl(l_run[sub], hi*4 + 1);
        float r2 = 1.f / __shfl(l_run[sub], hi*4 + 2);
        float r3 = 1.f / __shfl(l_run[sub], hi*4 + 3);
        float* Op = Out + ((size_t)bh * S_ + wq0 + sub*16) * D_;
        #pragma unroll
        for (int nb = 0; nb < 8; nb++){
          Op[(size_t)(hi*4 + 0)*D_ + nb*16 + ql] = o[sub][nb][0] * r0;
          Op[(size_t)(hi*4 + 1)*D_ + nb*16 + ql] = o[sub][nb][1] * r1;
          Op[(size_t)(hi*4 + 2)*D_ + nb*16 + ql] = o[sub][nb][2] * r2;
          Op[(size_t)(hi*4 + 3)*D_ + nb*16 + ql] = o[sub][nb][3] * r3;
        }
      }
    } else {
      const int slot = bh*36 + OFFT[qb - 4] + c;
      unsigned short* Po = Opart + (size_t)slot * (128*128);
      float* Ml = MLpart + (size_t)slot * 256;
      #pragma unroll
      for (int sub = 0; sub < 2; sub++){
        #pragma unroll
        for (int nb = 0; nb < 8; nb++){
          #pragma unroll
          for (int r = 0; r < 4; r++){
            int row = wave*32 + sub*16 + hi*4 + r;
            __bf16 bv = (__bf16)o[sub][nb][r];
            Po[row*128 + nb*16 + ql] = __builtin_bit_cast(unsigned short, bv);
          }
        }
        if (hi == 0){
          int row = wave*32 + sub*16 + ql;
          Ml[row*2 + 0] = m_run[sub];
          Ml[row*2 + 1] = l_run[sub];
        }
      }
    }
  }
}

// ---------- combine kernel: merge the 2-4 kv-chunks of qb>=4 ----------
__global__ __launch_bounds__(256)
void combine(const unsigned short* __restrict__ Opart,
             const float* __restrict__ MLpart, float* __restrict__ Out){
  const int bx = blockIdx.x;            // 0..383 = bh*12 + (qb-4)
  const int bh = bx / 12, qi = bx % 12, qb = qi + 4;
  const int nc = (2*qb + 9) >> 3;
  const int base = bh*36 + OFFT[qi];
  const int row  = threadIdx.x >> 1;
  const int half = threadIdx.x & 1;

  float m[4] = {-INFINITY,-INFINITY,-INFINITY,-INFINITY};
  float l[4] = {0.f,0.f,0.f,0.f};
  float M = -INFINITY;
  #pragma unroll
  for (int c = 0; c < 4; c++) if (c < nc){
    m[c] = MLpart[(size_t)(base+c)*256 + row*2];
    l[c] = MLpart[(size_t)(base+c)*256 + row*2 + 1];
    M = fmaxf(M, m[c]);
  }
  float w[4] = {0.f,0.f,0.f,0.f};
  float den = 0.f;
  #pragma unroll
  for (int c = 0; c < 4; c++) if (c < nc){
    w[c] = exp2f(m[c] - M);
    den += l[c]*w[c];
  }
  float inv = 1.f / den;

  float* Or = Out + ((size_t)bh * S_ + qb*128 + row) * D_ + half*64;
  #pragma unroll
  for (int cc = 0; cc < 64; cc += 8){
    float acc[8] = {0,0,0,0,0,0,0,0};
    #pragma unroll
    for (int c = 0; c < 4; c++) if (c < nc){
      const unsigned short* Pr = Opart + (size_t)(base+c)*16384 + row*128 + half*64 + cc;
      ushort4 a0 = *(const ushort4*)(Pr), a1 = *(const ushort4*)(Pr + 4);
      acc[0] += bf2f(a0.x)*w[c]; acc[1] += bf2f(a0.y)*w[c];
      acc[2] += bf2f(a0.z)*w[c]; acc[3] += bf2f(a0.w)*w[c];
      acc[4] += bf2f(a1.x)*w[c]; acc[5] += bf2f(a1.y)*w[c];
      acc[6] += bf2f(a1.z)*w[c]; acc[7] += bf2f(a1.w)*w[c];
    }
    #pragma unroll
    for (int j = 0; j < 8; j++) Or[cc + j] = acc[j]*inv;
  }
}

extern "C" void kernel_launch(void* const* d_in, const int* in_sizes, int n_in,
                              void* d_out, int out_size, void* d_ws, size_t ws_size,
                              hipStream_t stream){
  const float* Q = (const float*)d_in[0];
  const float* K = (const float*)d_in[1];
  const float* V = (const float*)d_in[2];
  float* Out = (float*)d_out;

  int* ctrl = (int*)d_ws;                                      // 512 B (zeroed by prep)
  unsigned short* Kb = (unsigned short*)((char*)d_ws + 4096);  // 16.78 MB
  unsigned short* Vt = Kb + (size_t)BH_ * S_ * D_;             // 16.78 MB
  unsigned short* Opart = Vt + (size_t)BH_ * S_ * D_;          // 1152 slots x 32KB = 37.75 MB
  float* MLpart = (float*)(Opart + (size_t)1152 * 128 * 128);  // 1.18 MB

  const size_t need = 4096 + (size_t)BH_*S_*D_*2*2
                    + (size_t)1152*128*128*2 + (size_t)1152*256*4;
  const int split = (ws_size >= need) ? 1 : 0;

  prep<<<dim3(S_/64, D_/64, BH_), 256, 0, stream>>>(K, V, Kb, Vt, ctrl);
  attn_fwd<<<768, 256, 0, stream>>>(Q, Kb, Vt, Out, Opart, MLpart, ctrl, split);
  if (split) combine<<<384, 256, 0, stream>>>(Opart, MLpart, Out);
}

// Round 9
// 101.648 us; speedup vs baseline: 3.2831x; 3.2831x over previous
//
#include <hip/hip_runtime.h>
#include <hip/hip_bf16.h>
#include <stdint.h>

typedef __attribute__((ext_vector_type(8)))  __bf16 bf16x8;
typedef __attribute__((ext_vector_type(16))) float  f32x16;

#define B_  2
#define H_  16
#define S_  2048
#define D_  128
#define BH_ (B_*H_)

__device__ __forceinline__ uint32_t f2bf1(float f){
  uint32_t u = __builtin_bit_cast(uint32_t, f);
  return (u + 0x7fffu + ((u >> 16) & 1u)) >> 16;
}
__device__ __forceinline__ uint32_t pk2(float a, float b){
  return f2bf1(a) | (f2bf1(b) << 16);
}
__device__ __forceinline__ float bf2f(unsigned short u){
  return __builtin_bit_cast(float, (uint32_t)u << 16);
}

// async global->LDS, 16B/lane, linear LDS dest
__device__ __forceinline__ void gld16(const void* g, void* l){
  __builtin_amdgcn_global_load_lds(
      (const __attribute__((address_space(1))) void*)g,
      (__attribute__((address_space(3))) void*)(uintptr_t)l, 16, 0, 0);
}

// Static unit table (R4-proven): code = qb*4 + mode; mode 0=full,
// 1=kv-chunk A (t in [0,qb]), 2=kv-chunk B (t in [qb+1,2qb+1], owns diag).
// LPT heavy-first order.
__device__ const unsigned char SPLIT_TAB[24] = {
  15*4+1,15*4+2, 7*4+0, 14*4+1,14*4+2, 13*4+1,13*4+2, 6*4+0,
  12*4+1,12*4+2, 11*4+1,11*4+2, 5*4+0, 10*4+1,10*4+2, 9*4+1,9*4+2,
  4*4+0, 8*4+1,8*4+2, 3*4+0, 2*4+0, 1*4+0, 0*4+0
};

// ---------- fused pre-pass: K->bf16 and V->Vt(bf16, transposed) ----------
__global__ void prep(const float* __restrict__ K, const float* __restrict__ V,
                     unsigned short* __restrict__ Kb, unsigned short* __restrict__ Vt){
  __shared__ __attribute__((aligned(16))) unsigned short t[64*68];
  const int kv0 = blockIdx.x * 64, d0 = blockIdx.y * 64, bh = blockIdx.z;
  const int tid = threadIdx.x;
  const float* Vp = V + (size_t)bh * S_ * D_;
  const float* Kp = K + (size_t)bh * S_ * D_;
  unsigned short* Ko = Kb + (size_t)bh * S_ * D_;
  for (int i = 0; i < 4; i++){
    int f = tid + i*256;
    int kv = f >> 4, c4 = f & 15;
    size_t idx = (size_t)(kv0+kv)*D_ + d0 + c4*4;
    float4 k = *(const float4*)(Kp + idx);
    *(uint2*)(Ko + idx) = make_uint2(pk2(k.x,k.y), pk2(k.z,k.w));
  }
  for (int i = 0; i < 4; i++){
    int f = tid + i*256;
    int kv = f >> 4, c4 = f & 15;
    float4 v = *(const float4*)(Vp + (size_t)(kv0+kv)*D_ + d0 + c4*4);
    *(uint2*)&t[kv*68 + c4*4] = make_uint2(pk2(v.x,v.y), pk2(v.z,v.w));
  }
  __syncthreads();
  unsigned short* Vo = Vt + (size_t)bh * D_ * S_;
  for (int i = 0; i < 4; i++){
    int g = tid + i*256;
    int d = g >> 4, c = g & 15, kv = c*4;
    ushort4 o;
    o.x = t[(kv+0)*68 + d];
    o.y = t[(kv+1)*68 + d];
    o.z = t[(kv+2)*68 + d];
    o.w = t[(kv+3)*68 + d];
    *(ushort4*)(Vo + (size_t)(d0+d)*S_ + kv0 + kv) = o;
  }
}

// ---------- flash-attention: 32x32 MFMA, in-register P, dbuf K/V ----------
// 4 waves x 32 q-rows = 128 q/block; KVBLK=64; 64KB LDS (2 blocks/CU).
__global__ __launch_bounds__(256, 2)
void attn_fwd(const float* __restrict__ Q, const unsigned short* __restrict__ Kb,
              const unsigned short* __restrict__ Vt, float* __restrict__ Out,
              unsigned short* __restrict__ Opart, float* __restrict__ MLpart,
              int splitFlag){
  __shared__ __attribute__((aligned(16))) unsigned short Klds[2][64*128]; // [kv][d] swz ^((kv&15)<<4)
  __shared__ __attribute__((aligned(16))) unsigned short Vlds[2][128*64]; // [d][kv] swz ^((d&7)<<4)

  const int bi = blockIdx.x;
  const int bh = (bi & 7) + 8*((bi >> 3) & 3);
  const int u  = bi >> 5;
  int qb, mode;
  if (splitFlag){ int c = SPLIT_TAB[u]; qb = c >> 2; mode = c & 3; }
  else { qb = (u < 8) ? (15 - u) : (u - 8); mode = 0; }

  const int tid  = threadIdx.x;
  const int wave = tid >> 6, lane = tid & 63;
  const int q32  = lane & 31, hf = lane >> 5;
  const int wq0  = qb*128 + wave*32;
  const int t0   = (mode == 2) ? qb + 1 : 0;
  const int tEnd = (mode == 1) ? qb + 1 : 2*qb + 2;
  const int dtw  = (mode == 1) ? (1 << 30) : (2*qb + (wave >> 1));
  const float qs = 0.08838834764831845f * 1.44269504088896f; // scale*log2(e)

  const char* Kg = (const char*)(Kb + (size_t)bh * S_ * D_);
  const char* Vg = (const char*)(Vt + (size_t)bh * D_ * S_);

  // staging source offsets (pre-swizzled; LDS dest linear p = wave*4096+i*1024+lane*16)
  // K row r = p>>8 (256B rows), swz col' = col ^ ((r&15)<<4)
  // V row d = p>>7 (128B rows), swz col' = col ^ ((d&7)<<4)
  uint32_t koff[4], voff[4];
  #pragma unroll
  for (int i = 0; i < 4; i++){
    int kr = wave*16 + i*4 + (lane >> 4);
    koff[i] = kr*256 + (((lane & 15) ^ (i*4 + (lane >> 4))) << 4);
    int vr = wave*32 + i*8 + (lane >> 3);
    voff[i] = vr*(S_*2) + (((lane & 7) ^ ((lane >> 3) & 7)) << 4);
  }

  auto stage = [&](int buf, int t){
    const char* kp = Kg + t*16384;
    const char* vp = Vg + t*128;
    char* kd = (char*)&Klds[buf][0] + wave*4096;
    char* vd = (char*)&Vlds[buf][0] + wave*4096;
    #pragma unroll
    for (int i = 0; i < 4; i++){
      gld16(kp + koff[i], kd + i*1024);
      gld16(vp + voff[i], vd + i*1024);
    }
  };

  // Q fragments, pre-scaled: lane holds Q[wq0+q32][ds*16 + hf*8 + j]
  uint4 qf[8];
  {
    const float* Qp = Q + ((size_t)bh * S_ + (wq0 + q32)) * D_ + hf*8;
    #pragma unroll
    for (int ds = 0; ds < 8; ds++){
      float4 a = *(const float4*)(Qp + ds*16);
      float4 b = *(const float4*)(Qp + ds*16 + 4);
      bf16x8 q8;
      q8[0] = (__bf16)(a.x*qs); q8[1] = (__bf16)(a.y*qs);
      q8[2] = (__bf16)(a.z*qs); q8[3] = (__bf16)(a.w*qs);
      q8[4] = (__bf16)(b.x*qs); q8[5] = (__bf16)(b.y*qs);
      q8[6] = (__bf16)(b.z*qs); q8[7] = (__bf16)(b.w*qs);
      qf[ds] = __builtin_bit_cast(uint4, q8);
    }
  }

  f32x16 o[4];
  #pragma unroll
  for (int db = 0; db < 4; db++) o[db] = (f32x16)(0.f);
  float m_run = -INFINITY, l_run = 0.f;

  stage(0, t0);
  __syncthreads();

  int cur = 0;
  for (int t = t0; t < tEnd; ++t){
    if (t + 1 < tEnd) stage(cur ^ 1, t + 1);   // prefetch; drains at end barrier

    if (t <= dtw){
      const bool diag = (t == dtw);
      const char* Kc = (const char*)&Klds[cur][0];
      const char* Vc = (const char*)&Vlds[cur][0];

      // ---- swapped QK^T: S^T = mfma(A=K, B=Q^T), 32x32x16, 2 kv-groups
      f32x16 sa0 = (f32x16)(0.f), sa1 = (f32x16)(0.f);
      __builtin_amdgcn_s_setprio(1);
      #pragma unroll
      for (int ds = 0; ds < 8; ds++){
        int c0 = (q32*256        + ds*32 + hf*16) ^ ((q32 & 15) << 4);
        int c1 = ((32+q32)*256   + ds*32 + hf*16) ^ ((q32 & 15) << 4);
        bf16x8 k0 = *(const bf16x8*)(Kc + c0);
        bf16x8 k1 = *(const bf16x8*)(Kc + c1);
        sa0 = __builtin_amdgcn_mfma_f32_32x32x16_bf16(
                k0, __builtin_bit_cast(bf16x8, qf[ds]), sa0, 0, 0, 0);
        sa1 = __builtin_amdgcn_mfma_f32_32x32x16_bf16(
                k1, __builtin_bit_cast(bf16x8, qf[ds]), sa1, 0, 0, 0);
      }
      __builtin_amdgcn_s_setprio(0);

      // ---- online softmax (log2 domain, defer-max); lane owns row q=q32,
      // kv coverage: own 32 (reg-mapped) + partner lane^32 holds the rest.
      float p[32];
      float pm = -INFINITY;
      const int q_abs = wq0 + q32;
      #pragma unroll
      for (int r = 0; r < 16; r++){
        float s0 = sa0[r], s1 = sa1[r];
        if (diag){
          int kvl = t*64 + (r & 3) + 8*(r >> 2) + 4*hf;
          if (kvl      > q_abs) s0 = -1e30f;
          if (kvl + 32 > q_abs) s1 = -1e30f;
        }
        p[r] = s0; p[16 + r] = s1;
        pm = fmaxf(pm, fmaxf(s0, s1));
      }
      pm = fmaxf(pm, __shfl_xor(pm, 32));
      if (__any(pm > m_run + 11.5f)){
        float mn  = fmaxf(m_run, pm);
        float fac = exp2f(m_run - mn);
        float fv[16];
        #pragma unroll
        for (int r = 0; r < 16; r++) fv[r] = __shfl(fac, (r & 3) + 8*(r >> 2) + 4*hf);
        #pragma unroll
        for (int db = 0; db < 4; db++)
          #pragma unroll
          for (int r = 0; r < 16; r++) o[db][r] *= fv[r];
        l_run *= fac;
        m_run = mn;
      }
      float rs = 0.f;
      #pragma unroll
      for (int i = 0; i < 32; i++){ p[i] = exp2f(p[i] - m_run); rs += p[i]; }
      rs += __shfl_xor(rs, 32);
      l_run += rs;

      // ---- pack P to bf16 pairs: W[M][t] = pk(kv=8M+4hf+2t, +1)
      uint32_t W[8][2];
      #pragma unroll
      for (int M = 0; M < 8; M++){
        #pragma unroll
        for (int tt = 0; tt < 2; tt++){
          float lo = p[(M >> 2)*16 + 4*(M & 3) + 2*tt];
          float hi = p[(M >> 2)*16 + 4*(M & 3) + 2*tt + 1];
          asm("v_cvt_pk_bf16_f32 %0, %1, %2" : "=v"(W[M][tt]) : "v"(lo), "v"(hi));
        }
      }

      // ---- PV: A = P (via permlane32_swap redistribution), B = V from LDS
      __builtin_amdgcn_s_setprio(1);
      #pragma unroll
      for (int Ks = 0; Ks < 4; Ks++){
        uint32_t d0 = W[2*Ks][0], d2 = W[2*Ks + 1][0];
        asm volatile("v_permlane32_swap_b32 %0, %1" : "+v"(d0), "+v"(d2));
        uint32_t d1 = W[2*Ks][1], d3 = W[2*Ks + 1][1];
        asm volatile("v_permlane32_swap_b32 %0, %1" : "+v"(d1), "+v"(d3));
        uint4 pw = make_uint4(d0, d1, d2, d3);
        bf16x8 paf = __builtin_bit_cast(bf16x8, pw);
        #pragma unroll
        for (int db = 0; db < 4; db++){
          int row = db*32 + q32;
          int vb = (row*128 + Ks*32 + hf*16) ^ ((row & 7) << 4);
          bf16x8 vf = *(const bf16x8*)(Vc + vb);
          o[db] = __builtin_amdgcn_mfma_f32_32x32x16_bf16(paf, vf, o[db], 0, 0, 0);
        }
      }
      __builtin_amdgcn_s_setprio(0);
    }

    __syncthreads();   // drains prefetch + publishes buf[cur^1]
    cur ^= 1;
  }

  // ---- epilogue
  if (mode == 0){
    float rl[16];
    #pragma unroll
    for (int r = 0; r < 16; r++)
      rl[r] = 1.f / __shfl(l_run, (r & 3) + 8*(r >> 2) + 4*hf);
    float* Op = Out + ((size_t)bh * S_ + wq0) * D_;
    #pragma unroll
    for (int db = 0; db < 4; db++){
      #pragma unroll
      for (int r = 0; r < 16; r++){
        int qrow = (r & 3) + 8*(r >> 2) + 4*hf;
        Op[(size_t)qrow*D_ + db*32 + q32] = o[db][r] * rl[r];
      }
    }
  } else {
    const int slot = (bh*8 + (qb - 8))*2 + (mode - 1);
    unsigned short* Po = Opart + (size_t)slot * (128*128);
    float* Ml = MLpart + (size_t)slot * 256;
    #pragma unroll
    for (int db = 0; db < 4; db++){
      #pragma unroll
      for (int r = 0; r < 16; r++){
        int row = wave*32 + (r & 3) + 8*(r >> 2) + 4*hf;
        __bf16 bv = (__bf16)o[db][r];
        Po[row*128 + db*32 + q32] = __builtin_bit_cast(unsigned short, bv);
      }
    }
    if (hf == 0){
      Ml[(wave*32 + q32)*2 + 0] = m_run;
      Ml[(wave*32 + q32)*2 + 1] = l_run;
    }
  }
}

// ---------- combine kernel: merge the two kv-chunks of qb>=8 ----------
__global__ __launch_bounds__(256)
void combine(const unsigned short* __restrict__ Opart,
             const float* __restrict__ MLpart, float* __restrict__ Out){
  const int blk = blockIdx.x;           // 0..255 = bh*8 + (qb-8)
  const int bh = blk >> 3, qq = blk & 7;
  const unsigned short* A  = Opart + (size_t)(blk*2) * (128*128);
  const unsigned short* Bp = A + 128*128;
  const float* MA = MLpart + (size_t)(blk*2) * 256;
  const float* MB = MA + 256;

  const int row  = threadIdx.x >> 1;
  const int half = threadIdx.x & 1;
  float mA = MA[row*2], lA = MA[row*2 + 1];
  float mB = MB[row*2], lB = MB[row*2 + 1];
  float M  = fmaxf(mA, mB);
  float wA = exp2f(mA - M), wB = exp2f(mB - M);
  float inv = 1.f / (lA*wA + lB*wB);
  wA *= inv; wB *= inv;

  const unsigned short* Ar = A  + row*128 + half*64;
  const unsigned short* Br = Bp + row*128 + half*64;
  float* Or = Out + ((size_t)bh * S_ + (qq + 8)*128 + row) * D_ + half*64;
  #pragma unroll
  for (int c = 0; c < 64; c += 8){
    ushort4 a0 = *(const ushort4*)(Ar + c), a1 = *(const ushort4*)(Ar + c + 4);
    ushort4 b0 = *(const ushort4*)(Br + c), b1 = *(const ushort4*)(Br + c + 4);
    const unsigned short av[8] = {a0.x,a0.y,a0.z,a0.w,a1.x,a1.y,a1.z,a1.w};
    const unsigned short bv[8] = {b0.x,b0.y,b0.z,b0.w,b1.x,b1.y,b1.z,b1.w};
    #pragma unroll
    for (int j = 0; j < 8; j++){
      Or[c + j] = bf2f(av[j])*wA + bf2f(bv[j])*wB;
    }
  }
}

extern "C" void kernel_launch(void* const* d_in, const int* in_sizes, int n_in,
                              void* d_out, int out_size, void* d_ws, size_t ws_size,
                              hipStream_t stream){
  const float* Q = (const float*)d_in[0];
  const float* K = (const float*)d_in[1];
  const float* V = (const float*)d_in[2];
  float* Out = (float*)d_out;

  unsigned short* Kb = (unsigned short*)d_ws;                 // 16.78 MB
  unsigned short* Vt = Kb + (size_t)BH_ * S_ * D_;            // 16.78 MB
  unsigned short* Opart = Vt + (size_t)BH_ * S_ * D_;         // 512 x 32KB = 16.78 MB
  float* MLpart = (float*)(Opart + (size_t)512 * 128 * 128);  // 0.52 MB

  const size_t need = (size_t)BH_*S_*D_*2*3 + (size_t)512*256*4;
  const int split = (ws_size >= need) ? 1 : 0;

  prep<<<dim3(S_/64, D_/64, BH_), 256, 0, stream>>>(K, V, Kb, Vt);
  attn_fwd<<<split ? 768 : 512, 256, 0, stream>>>(Q, Kb, Vt, Out, Opart, MLpart, split);
  if (split) combine<<<256, 256, 0, stream>>>(Opart, MLpart, Out);
}